// Round 5
// baseline (122.371 us; speedup 1.0000x reference)
//
#include <hip/hip_runtime.h>

typedef float v2f __attribute__((ext_vector_type(2)));

#define NB 32
#define N0 20000
#define N1 10000
#define N2 10000
#define NF4_A 10000        // float4s per (b, side) beta_0 stream
#define NF4_E0 5000        // float4s of ext0 per b
#define NF4_E 10000        // float4s of ext0+ext1 per b
#define NCH 157            // ceil(10000/64): 64-float4 chunks per stream
#define T_A 8              // A-role chunk stride (8 tchunk blocks/stream)
#define T_E 8              // E-role chunk stride
#define KC 8               // centers per wave
#define SENT 3.0e4f        // sentinel: per-term contribution ~ -1e-10

// Unified exact kernel: grid = 2048 blocks = 256 CU x 8 blocks/CU, one
// residency round. Slots [0,1024) = A-role (beta_0 points, 2-D exact);
// slots [1024,2048) = E-role (ext points: u==1, so L1 reduces to a 1-D
// formula -- evaluated EXACTLY, replacing the old 4096-bin histogram
// whose serial per-CU chain was the 54us critical path / 64% idle tail).
// Both ranges are multiples of 8 -> even XCD spread (blockIdx%8 = XCD;
// R1 lesson). No LDS, no __syncthreads anywhere: every wave owns its own
// 8-center group and atomicAdds into memset-zeroed out[0..4095].
__global__ __launch_bounds__(256, 8) void hat_kernel(
    const float* __restrict__ up0, const float* __restrict__ down0,
    const float* __restrict__ ext0, const float* __restrict__ ext1,
    const float* __restrict__ centers, const float* __restrict__ radius,
    float* __restrict__ out)
{
    const int tid  = threadIdx.x;
    const int lane = tid & 63;
    const int wave = tid >> 6;
    const float r  = fabsf(radius[0]);
    const int slot = blockIdx.x;

    float a1[KC];
    int outBase;

    if (slot < 1024) {
        // ============ A-role: beta_0 points, exact 2-D ============
        // slot = (b<<5) | (side<<4) | (half<<3) | tchunk
        const int tchunk = slot & 7;
        const int half   = (slot >> 3) & 1;
        const int side   = (slot >> 4) & 1;
        const int b      = slot >> 5;
        const int cbase  = (half * 4 + wave) * KC;   // per-wave center group
        outBase = b*128 + side*64 + cbase;

        v2f nuc[KC], nvc[KC];
        #pragma unroll
        for (int k = 0; k < KC; ++k) {
            const float cx = centers[2*(cbase+k)];
            const float cy = centers[2*(cbase+k)+1];
            nuc[k] = (v2f){-(cx + cy), -(cx + cy)};
            nvc[k] = (v2f){-(cx - cy), -(cx - cy)};
        }

        const float4* base0 = (const float4*)((side == 0 ? up0 : down0) + (size_t)b * (N0*2));

        v2f acc[KC];
        #pragma unroll
        for (int k = 0; k < KC; ++k) acc[k] = (v2f){0.f, 0.f};
        const v2f one2 = (v2f){1.f, 1.f};

        // All 4 waves of this block walk the SAME chunk stream (L1 reuse),
        // each evaluating its own 8-center group.
        for (int t = tchunk; t < NCH; t += T_A) {
            const int i = t*64 + lane;      // float4 index = two points
            v2f u_, v_;
            if (i < NF4_A) {
                const float4 q = base0[i];
                u_ = (v2f){q.x + q.y, q.z + q.w};
                v_ = (v2f){q.x - q.y, q.z - q.w};
            } else {
                u_ = (v2f){SENT, SENT};
                v_ = (v2f){0.f, 0.f};
            }

            #pragma unroll
            for (int k = 0; k < KC; ++k) {
                const v2f du = u_ + nuc[k];
                const v2f dv = v_ + nvc[k];
                const float tt0 = fmaxf(fabsf(du.x), fabsf(dv.x));
                const float tt1 = fmaxf(fabsf(du.y), fabsf(dv.y));
                const v2f tt = (v2f){tt0, tt1};
                const v2f d1 = tt + one2;
                const float rn0 = r - tt0;
                const float rn1 = r - tt1;
                const v2f d2 = (v2f){1.f + fabsf(rn0), 1.f + fabsf(rn1)};
                const v2f dd  = d1 * d2;
                const v2f num = d2 - d1;
                const v2f rc  = (v2f){__builtin_amdgcn_rcpf(dd.x),
                                      __builtin_amdgcn_rcpf(dd.y)};
                acc[k] = __builtin_elementwise_fma(num, rc, acc[k]);
            }
        }

        #pragma unroll
        for (int k = 0; k < KC; ++k) a1[k] = acc[k].x + acc[k].y;
    } else {
        // ============ E-role: ext points, exact 1-D (u == 1) ============
        // Each derived point (w, 1-w): u = 1, v = 2w-1.
        // L1 = max(|1-(cx+cy)|, |2w - (1+cx-cy)|) = max(Ak, |2w + nm2k|).
        // eid = (b<<5) | (c4<<3) | echunk; combo = c4*4+wave covers all 16
        // (side, 8-center-group) pairs; side = combo&1 (0 = up uses y).
        const int eid    = slot - 1024;
        const int echunk = eid & 7;
        const int c4     = (eid >> 3) & 3;
        const int b      = eid >> 5;
        const int combo  = c4 * 4 + wave;
        const int side   = combo & 1;
        const int cbase  = (combo >> 1) * KC;
        outBase = b*128 + side*64 + cbase;

        float Ak[KC], nm2[KC];
        #pragma unroll
        for (int k = 0; k < KC; ++k) {
            const float cx = centers[2*(cbase+k)];
            const float cy = centers[2*(cbase+k)+1];
            Ak[k]  = fabsf(1.0f - (cx + cy));
            nm2[k] = -(1.0f + (cx - cy));
        }

        const float4* e0 = (const float4*)(ext0 + (size_t)b * (N1*2));
        const float4* e1 = (const float4*)(ext1 + (size_t)b * (N2*2));

        v2f acc[KC];
        #pragma unroll
        for (int k = 0; k < KC; ++k) acc[k] = (v2f){0.f, 0.f};
        const v2f one2 = (v2f){1.f, 1.f};

        for (int t = echunk; t < NCH; t += T_E) {
            // flat per-lane select (simple CFG; exec-masked loads)
            const int i = t*64 + lane;
            float4 q;
            if (i < NF4_E0)     q = e0[i];
            else if (i < NF4_E) q = e1[i - NF4_E0];
            else                q = (float4){SENT, SENT, SENT, SENT};

            // side 0 (up) uses y components, side 1 (down) uses x.
            const v2f w = (side == 0) ? (v2f){q.y, q.w} : (v2f){q.x, q.z};

            #pragma unroll
            for (int k = 0; k < KC; ++k) {
                const float dv0 = fmaf(2.0f, w.x, nm2[k]);
                const float dv1 = fmaf(2.0f, w.y, nm2[k]);
                const float tt0 = fmaxf(Ak[k], fabsf(dv0));
                const float tt1 = fmaxf(Ak[k], fabsf(dv1));
                const v2f tt = (v2f){tt0, tt1};
                const v2f d1 = tt + one2;
                const float rn0 = r - tt0;
                const float rn1 = r - tt1;
                const v2f d2 = (v2f){1.f + fabsf(rn0), 1.f + fabsf(rn1)};
                const v2f dd  = d1 * d2;
                const v2f num = d2 - d1;
                const v2f rc  = (v2f){__builtin_amdgcn_rcpf(dd.x),
                                      __builtin_amdgcn_rcpf(dd.y)};
                acc[k] = __builtin_elementwise_fma(num, rc, acc[k]);
            }
        }

        #pragma unroll
        for (int k = 0; k < KC; ++k) a1[k] = acc[k].x + acc[k].y;
    }

    // ======= shared KC=8 butterfly (R7/R8-validated): value (lane>>3)&7
    // ======= lands in a1[0] of lanes with (lane&7)==0
    {
        #pragma unroll
        for (int k = 0; k < 4; ++k) {
            const bool hi = lane & 32;
            const float send = hi ? a1[k]   : a1[k+4];
            const float keep = hi ? a1[k+4] : a1[k];
            a1[k] = keep + __shfl_xor(send, 32, 64);
        }
        #pragma unroll
        for (int k = 0; k < 2; ++k) {
            const bool hi = lane & 16;
            const float send = hi ? a1[k]   : a1[k+2];
            const float keep = hi ? a1[k+2] : a1[k];
            a1[k] = keep + __shfl_xor(send, 16, 64);
        }
        {
            const bool hi = lane & 8;
            const float send = hi ? a1[0] : a1[1];
            const float keep = hi ? a1[1] : a1[0];
            a1[0] = keep + __shfl_xor(send, 8, 64);
        }
        a1[0] += __shfl_xor(a1[0], 4, 64);
        a1[0] += __shfl_xor(a1[0], 2, 64);
        a1[0] += __shfl_xor(a1[0], 1, 64);
    }
    if ((lane & 7) == 0) {
        atomicAdd(&out[outBase + (lane >> 3)], a1[0]);
    }
}

__global__ __launch_bounds__(256) void tpl_kernel(float* __restrict__ out)
{
    __shared__ float red[256];
    float s = 0.f;
    for (int i = threadIdx.x; i < NB*64; i += 256) {
        const int b = i >> 6, k = i & 63;
        const float d = out[b*128 + k] - out[b*128 + 64 + k];
        s = fmaf(d, d, s);
    }
    red[threadIdx.x] = s;
    __syncthreads();
    for (int w = 128; w > 0; w >>= 1) {
        if (threadIdx.x < w) red[threadIdx.x] += red[threadIdx.x + w];
        __syncthreads();
    }
    if (threadIdx.x == 0) out[NB*128] = -red[0];
}

extern "C" void kernel_launch(void* const* d_in, const int* in_sizes, int n_in,
                              void* d_out, int out_size, void* d_ws, size_t ws_size,
                              hipStream_t stream) {
    const float* up0     = (const float*)d_in[0];
    const float* down0   = (const float*)d_in[1];
    const float* ext0    = (const float*)d_in[2];
    const float* ext1    = (const float*)d_in[3];
    const float* centers = (const float*)d_in[4];
    const float* radius  = (const float*)d_in[5];
    float* out = (float*)d_out;

    // accumulator region must start at zero (harness poisons d_out with 0xAA)
    hipMemsetAsync(out, 0, NB * 128 * sizeof(float), stream);

    hat_kernel<<<dim3(2048), dim3(256), 0, stream>>>(
        up0, down0, ext0, ext1, centers, radius, out);
    tpl_kernel<<<1, 256, 0, stream>>>(out);
}

// Round 6
// 121.267 us; speedup vs baseline: 1.0091x; 1.0091x over previous
//
#include <hip/hip_runtime.h>

typedef float v2f __attribute__((ext_vector_type(2)));

#define NB 32
#define N0 20000
#define N1 10000
#define N2 10000
#define NF4_A 10000        // float4s per (b, side) beta_0 stream
#define NF4_E0 5000        // float4s of ext0 per b
#define NF4_E 10000        // float4s of ext0+ext1 per b
#define NCH 157            // ceil(10000/64): 64-float4 chunks per stream
#define T_A 8              // A-role chunk stride
#define T_E 8              // E-role chunk stride
#define KC 8               // centers per wave
#define SENT 3.0e4f        // sentinel: per-term contribution ~ -1e-10

// R6: same 2048-block unified-exact structure as R5 (A-role slots [0,1024),
// E-role slots [1024,2048), no LDS / no syncthreads, KC=8 per wave).
// Change: loads are UNCONDITIONAL (clamped index) + explicitly prefetched
// one iteration ahead. R5's per-lane-conditional loads sat right before
// their use, so every iteration exposed load latency and the 8 waves/SIMD
// stalled in lockstep (VALUBusy 69%, ~16us idle). Tail lanes are masked to
// SENT inside a wave-uniform branch taken only on the partial chunk t=156.
// VGPR headroom: launch_bounds(256,8) caps at 64; R5 used 32.
__global__ __launch_bounds__(256, 8) void hat_kernel(
    const float* __restrict__ up0, const float* __restrict__ down0,
    const float* __restrict__ ext0, const float* __restrict__ ext1,
    const float* __restrict__ centers, const float* __restrict__ radius,
    float* __restrict__ out)
{
    const int tid  = threadIdx.x;
    const int lane = tid & 63;
    const int wave = tid >> 6;
    const float r  = fabsf(radius[0]);
    const int slot = blockIdx.x;

    float a1[KC];
    int outBase;

    if (slot < 1024) {
        // ============ A-role: beta_0 points, exact 2-D ============
        // slot = (b<<5) | (side<<4) | (half<<3) | tchunk
        const int tchunk = slot & 7;
        const int half   = (slot >> 3) & 1;
        const int side   = (slot >> 4) & 1;
        const int b      = slot >> 5;
        const int cbase  = (half * 4 + wave) * KC;   // per-wave center group
        outBase = b*128 + side*64 + cbase;

        v2f nuc[KC], nvc[KC];
        #pragma unroll
        for (int k = 0; k < KC; ++k) {
            const float cx = centers[2*(cbase+k)];
            const float cy = centers[2*(cbase+k)+1];
            nuc[k] = (v2f){-(cx + cy), -(cx + cy)};
            nvc[k] = (v2f){-(cx - cy), -(cx - cy)};
        }

        const float4* base0 = (const float4*)((side == 0 ? up0 : down0) + (size_t)b * (N0*2));

        v2f acc[KC];
        #pragma unroll
        for (int k = 0; k < KC; ++k) acc[k] = (v2f){0.f, 0.f};
        const v2f one2 = (v2f){1.f, 1.f};

        // Unconditional clamped load, prefetched one iteration ahead.
        float4 q = base0[min(tchunk*64 + lane, NF4_A - 1)];
        for (int t = tchunk; t < NCH; t += T_A) {
            const float4 qc = q;
            const int tn = t + T_A;
            if (tn < NCH) {                       // wave-uniform
                q = base0[min(tn*64 + lane, NF4_A - 1)];
            }

            v2f u_ = (v2f){qc.x + qc.y, qc.z + qc.w};
            v2f v_ = (v2f){qc.x - qc.y, qc.z - qc.w};
            if (t*64 + 63 >= NF4_A) {             // wave-uniform: only t==156
                const bool bad = (t*64 + lane) >= NF4_A;
                u_.x = bad ? SENT : u_.x;  u_.y = bad ? SENT : u_.y;
                v_.x = bad ? 0.f  : v_.x;  v_.y = bad ? 0.f  : v_.y;
            }

            #pragma unroll
            for (int k = 0; k < KC; ++k) {
                const v2f du = u_ + nuc[k];
                const v2f dv = v_ + nvc[k];
                const float tt0 = fmaxf(fabsf(du.x), fabsf(dv.x));
                const float tt1 = fmaxf(fabsf(du.y), fabsf(dv.y));
                const v2f tt = (v2f){tt0, tt1};
                const v2f d1 = tt + one2;
                const float rn0 = r - tt0;
                const float rn1 = r - tt1;
                const v2f d2 = (v2f){1.f + fabsf(rn0), 1.f + fabsf(rn1)};
                const v2f dd  = d1 * d2;
                const v2f num = d2 - d1;
                const v2f rc  = (v2f){__builtin_amdgcn_rcpf(dd.x),
                                      __builtin_amdgcn_rcpf(dd.y)};
                acc[k] = __builtin_elementwise_fma(num, rc, acc[k]);
            }
        }

        #pragma unroll
        for (int k = 0; k < KC; ++k) a1[k] = acc[k].x + acc[k].y;
    } else {
        // ============ E-role: ext points, exact 1-D (u == 1) ============
        // point (w, 1-w): u=1, v=2w-1; L1 = max(Ak, |2w + nm2k|).
        // eid = (b<<5) | (c4<<3) | echunk; combo = c4*4+wave covers all 16
        // (side, 8-center-group) pairs; side = combo&1 (0 = up uses y).
        const int eid    = slot - 1024;
        const int echunk = eid & 7;
        const int c4     = (eid >> 3) & 3;
        const int b      = eid >> 5;
        const int combo  = c4 * 4 + wave;
        const int side   = combo & 1;
        const int cbase  = (combo >> 1) * KC;
        outBase = b*128 + side*64 + cbase;

        float Ak[KC], nm2[KC];
        #pragma unroll
        for (int k = 0; k < KC; ++k) {
            const float cx = centers[2*(cbase+k)];
            const float cy = centers[2*(cbase+k)+1];
            Ak[k]  = fabsf(1.0f - (cx + cy));
            nm2[k] = -(1.0f + (cx - cy));
        }

        const float4* e0 = (const float4*)(ext0 + (size_t)b * (N1*2));
        const float4* e1 = (const float4*)(ext1 + (size_t)b * (N2*2));

        v2f acc[KC];
        #pragma unroll
        for (int k = 0; k < KC; ++k) acc[k] = (v2f){0.f, 0.f};
        const v2f one2 = (v2f){1.f, 1.f};

        // Unconditional load via single clamped pointer-select, prefetched.
        #define ELOAD(T) (*((((T)*64 + lane) < NF4_E0)                          \
            ? (e0 + min((T)*64 + lane, NF4_E0 - 1))                             \
            : (e1 + (min((T)*64 + lane, NF4_E - 1) - NF4_E0))))

        float4 q = ELOAD(echunk);
        for (int t = echunk; t < NCH; t += T_E) {
            const float4 qc = q;
            const int tn = t + T_E;
            if (tn < NCH) {                       // wave-uniform
                q = ELOAD(tn);
            }

            // side 0 (up) uses y components, side 1 (down) uses x.
            v2f w = (side == 0) ? (v2f){qc.y, qc.w} : (v2f){qc.x, qc.z};
            if (t*64 + 63 >= NF4_E) {             // wave-uniform: only t==156
                const bool bad = (t*64 + lane) >= NF4_E;
                w.x = bad ? SENT : w.x;  w.y = bad ? SENT : w.y;
            }

            #pragma unroll
            for (int k = 0; k < KC; ++k) {
                const float dv0 = fmaf(2.0f, w.x, nm2[k]);
                const float dv1 = fmaf(2.0f, w.y, nm2[k]);
                const float tt0 = fmaxf(Ak[k], fabsf(dv0));
                const float tt1 = fmaxf(Ak[k], fabsf(dv1));
                const v2f tt = (v2f){tt0, tt1};
                const v2f d1 = tt + one2;
                const float rn0 = r - tt0;
                const float rn1 = r - tt1;
                const v2f d2 = (v2f){1.f + fabsf(rn0), 1.f + fabsf(rn1)};
                const v2f dd  = d1 * d2;
                const v2f num = d2 - d1;
                const v2f rc  = (v2f){__builtin_amdgcn_rcpf(dd.x),
                                      __builtin_amdgcn_rcpf(dd.y)};
                acc[k] = __builtin_elementwise_fma(num, rc, acc[k]);
            }
        }
        #undef ELOAD

        #pragma unroll
        for (int k = 0; k < KC; ++k) a1[k] = acc[k].x + acc[k].y;
    }

    // ======= shared KC=8 butterfly (R7/R8-validated): value (lane>>3)&7
    // ======= lands in a1[0] of lanes with (lane&7)==0
    {
        #pragma unroll
        for (int k = 0; k < 4; ++k) {
            const bool hi = lane & 32;
            const float send = hi ? a1[k]   : a1[k+4];
            const float keep = hi ? a1[k+4] : a1[k];
            a1[k] = keep + __shfl_xor(send, 32, 64);
        }
        #pragma unroll
        for (int k = 0; k < 2; ++k) {
            const bool hi = lane & 16;
            const float send = hi ? a1[k]   : a1[k+2];
            const float keep = hi ? a1[k+2] : a1[k];
            a1[k] = keep + __shfl_xor(send, 16, 64);
        }
        {
            const bool hi = lane & 8;
            const float send = hi ? a1[0] : a1[1];
            const float keep = hi ? a1[1] : a1[0];
            a1[0] = keep + __shfl_xor(send, 8, 64);
        }
        a1[0] += __shfl_xor(a1[0], 4, 64);
        a1[0] += __shfl_xor(a1[0], 2, 64);
        a1[0] += __shfl_xor(a1[0], 1, 64);
    }
    if ((lane & 7) == 0) {
        atomicAdd(&out[outBase + (lane >> 3)], a1[0]);
    }
}

__global__ __launch_bounds__(256) void tpl_kernel(float* __restrict__ out)
{
    __shared__ float red[256];
    float s = 0.f;
    for (int i = threadIdx.x; i < NB*64; i += 256) {
        const int b = i >> 6, k = i & 63;
        const float d = out[b*128 + k] - out[b*128 + 64 + k];
        s = fmaf(d, d, s);
    }
    red[threadIdx.x] = s;
    __syncthreads();
    for (int w = 128; w > 0; w >>= 1) {
        if (threadIdx.x < w) red[threadIdx.x] += red[threadIdx.x + w];
        __syncthreads();
    }
    if (threadIdx.x == 0) out[NB*128] = -red[0];
}

extern "C" void kernel_launch(void* const* d_in, const int* in_sizes, int n_in,
                              void* d_out, int out_size, void* d_ws, size_t ws_size,
                              hipStream_t stream) {
    const float* up0     = (const float*)d_in[0];
    const float* down0   = (const float*)d_in[1];
    const float* ext0    = (const float*)d_in[2];
    const float* ext1    = (const float*)d_in[3];
    const float* centers = (const float*)d_in[4];
    const float* radius  = (const float*)d_in[5];
    float* out = (float*)d_out;

    // accumulator region must start at zero (harness poisons d_out with 0xAA)
    hipMemsetAsync(out, 0, NB * 128 * sizeof(float), stream);

    hat_kernel<<<dim3(2048), dim3(256), 0, stream>>>(
        up0, down0, ext0, ext1, centers, radius, out);
    tpl_kernel<<<1, 256, 0, stream>>>(out);
}

// Round 7
// 109.725 us; speedup vs baseline: 1.1153x; 1.1052x over previous
//
#include <hip/hip_runtime.h>

typedef float v2f __attribute__((ext_vector_type(2)));

#define NB 32
#define N0 20000
#define N1 10000
#define N2 10000
#define NF4_A 10000        // float4s per (b, side) beta_0 stream
#define NF4_E0 5000        // float4s of ext0 per b
#define NF4_E 10000        // float4s of ext0+ext1 per b
#define NCH 157            // ceil(10000/64): 64-float4 chunks per A stream
#define T_A 8              // A-role chunk stride
#define KC_A 8             // centers per A wave
#define KC_B 16            // centers per E block
#define NBINS 4096
#define SENT 3.0e4f        // sentinel: per-term contribution ~ -1e-10

// R7: issue-bound post-mortem (R5/R6 busy ~37-40us of 53) -> cut E work via
// the R0-R2-validated 4096-bin histogram, but with BALANCED decomposition:
// grid = 1280 = 256 E-blocks (build own hist over all 20000 ext pts [40
// cheap iters], eval only 16 centers x 16 bins/thread) + 1024 A-blocks
// (R6 exact path verbatim). Per CU: 1 E + 4 A, walls ~equal (~3-4us),
// all co-resident (16.6KB LDS x 5 = 83KB). Both ranges XCD-even.
// E saves ~12us of issue (82M point-evals -> 16.8M bin-evals + 1.3M rcp).
__global__ __launch_bounds__(256, 8) void hat_kernel(
    const float* __restrict__ up0, const float* __restrict__ down0,
    const float* __restrict__ ext0, const float* __restrict__ ext1,
    const float* __restrict__ centers, const float* __restrict__ radius,
    float* __restrict__ out)
{
    const int tid  = threadIdx.x;
    const int lane = tid & 63;
    const int wave = tid >> 6;
    const float r  = fabsf(radius[0]);
    const int slot = blockIdx.x;

    __shared__ unsigned hist[NBINS];     // 16 KB (E-role)
    __shared__ float    red[4 * KC_B];   // E-role cross-wave reduction

    if (slot < 256) {
        // ============ E-role: ext points, 1-D binned (R2-validated) ========
        const int id   = slot;
        const int cc   = id & 3;         // 4 chunks of 16 centers
        const int side = (id >> 2) & 1;  // 0 = up (use y), 1 = down (use x)
        const int b    = id >> 3;
        const int cbase = cc * KC_B;

        for (int j = tid; j < NBINS; j += 256) hist[j] = 0;
        __syncthreads();

        // Build: one pass over ext0|ext1 as float4 (2 points each).
        const float4* e0 = (const float4*)(ext0 + (size_t)b * (N1*2));
        const float4* e1 = (const float4*)(ext1 + (size_t)b * (N2*2));
        for (int i = tid; i < NF4_E; i += 256) {
            const float4 q = (i < NF4_E0) ? e0[i] : e1[i - NF4_E0];
            const float vv0 = (side == 0) ? q.y : q.x;
            const float vv1 = (side == 0) ? q.w : q.z;
            int b0 = (int)(vv0 * (float)NBINS);
            int b1 = (int)(vv1 * (float)NBINS);
            b0 = min(max(b0, 0), NBINS - 1);
            b1 = min(max(b1, 0), NBINS - 1);
            atomicAdd(&hist[b0], 1u);
            atomicAdd(&hist[b1], 1u);
        }
        __syncthreads();

        // centers: n_k(vv) = max(|1-(cx+cy)|, 2|vv - (1+cx-cy)/2|)
        float Ak[KC_B], mk[KC_B];
        #pragma unroll
        for (int k = 0; k < KC_B; ++k) {
            const float cx = centers[2*(cbase+k)];
            const float cy = centers[2*(cbase+k)+1];
            Ak[k] = fabsf(1.0f - (cx + cy));
            mk[k] = 0.5f * (1.0f + (cx - cy));
        }

        float part[KC_B];
        #pragma unroll
        for (int k = 0; k < KC_B; ++k) part[k] = 0.f;

        #pragma unroll
        for (int jj = 0; jj < NBINS/256; ++jj) {
            const int j = jj*256 + tid;
            const float cntf = (float)hist[j];
            const float vvj  = ((float)j + 0.5f) * (1.0f/(float)NBINS);
            #pragma unroll
            for (int k = 0; k < KC_B; ++k) {
                const float s  = vvj - mk[k];
                const float tt = fmaxf(Ak[k], 2.0f*fabsf(s));
                const float d1 = 1.0f + tt;
                const float rn = r - tt;
                const float d2 = 1.0f + fabsf(rn);
                const float rc = __builtin_amdgcn_rcpf(d1 * d2);
                part[k] = fmaf(cntf * (d2 - d1), rc, part[k]);
            }
        }

        // KC=16 butterfly (R2-validated): center (lane>>2)&15 in part[0]
        {
            #pragma unroll
            for (int k = 0; k < 8; ++k) {
                const bool hi = lane & 32;
                const float send = hi ? part[k]   : part[k+8];
                const float keep = hi ? part[k+8] : part[k];
                part[k] = keep + __shfl_xor(send, 32, 64);
            }
            #pragma unroll
            for (int k = 0; k < 4; ++k) {
                const bool hi = lane & 16;
                const float send = hi ? part[k]   : part[k+4];
                const float keep = hi ? part[k+4] : part[k];
                part[k] = keep + __shfl_xor(send, 16, 64);
            }
            #pragma unroll
            for (int k = 0; k < 2; ++k) {
                const bool hi = lane & 8;
                const float send = hi ? part[k]   : part[k+2];
                const float keep = hi ? part[k+2] : part[k];
                part[k] = keep + __shfl_xor(send, 8, 64);
            }
            {
                const bool hi = lane & 4;
                const float send = hi ? part[0] : part[1];
                const float keep = hi ? part[1] : part[0];
                part[0] = keep + __shfl_xor(send, 4, 64);
            }
            part[0] += __shfl_xor(part[0], 2, 64);
            part[0] += __shfl_xor(part[0], 1, 64);
        }
        if ((lane & 3) == 0) red[wave * KC_B + (lane >> 2)] = part[0];
        __syncthreads();
        if (tid < KC_B) {
            const float s = red[tid] + red[KC_B + tid] + red[2*KC_B + tid] + red[3*KC_B + tid];
            atomicAdd(&out[b*128 + side*64 + cbase + tid], s);
        }
        return;
    }

    // ============ A-role: beta_0 points, exact 2-D (R6-validated) ============
    // aid = (b<<5) | (side<<4) | (half<<3) | tchunk
    const int aid    = slot - 256;
    const int tchunk = aid & 7;
    const int half   = (aid >> 3) & 1;
    const int side   = (aid >> 4) & 1;
    const int b      = aid >> 5;
    const int cbase  = (half * 4 + wave) * KC_A;   // per-wave center group
    const int outBase = b*128 + side*64 + cbase;

    v2f nuc[KC_A], nvc[KC_A];
    #pragma unroll
    for (int k = 0; k < KC_A; ++k) {
        const float cx = centers[2*(cbase+k)];
        const float cy = centers[2*(cbase+k)+1];
        nuc[k] = (v2f){-(cx + cy), -(cx + cy)};
        nvc[k] = (v2f){-(cx - cy), -(cx - cy)};
    }

    const float4* base0 = (const float4*)((side == 0 ? up0 : down0) + (size_t)b * (N0*2));

    v2f acc[KC_A];
    #pragma unroll
    for (int k = 0; k < KC_A; ++k) acc[k] = (v2f){0.f, 0.f};
    const v2f one2 = (v2f){1.f, 1.f};

    // Unconditional clamped load, prefetched one iteration ahead.
    float4 q = base0[min(tchunk*64 + lane, NF4_A - 1)];
    for (int t = tchunk; t < NCH; t += T_A) {
        const float4 qc = q;
        const int tn = t + T_A;
        if (tn < NCH) {                       // wave-uniform
            q = base0[min(tn*64 + lane, NF4_A - 1)];
        }

        v2f u_ = (v2f){qc.x + qc.y, qc.z + qc.w};
        v2f v_ = (v2f){qc.x - qc.y, qc.z - qc.w};
        if (t*64 + 63 >= NF4_A) {             // wave-uniform: only t==156
            const bool bad = (t*64 + lane) >= NF4_A;
            u_.x = bad ? SENT : u_.x;  u_.y = bad ? SENT : u_.y;
            v_.x = bad ? 0.f  : v_.x;  v_.y = bad ? 0.f  : v_.y;
        }

        #pragma unroll
        for (int k = 0; k < KC_A; ++k) {
            const v2f du = u_ + nuc[k];
            const v2f dv = v_ + nvc[k];
            const float tt0 = fmaxf(fabsf(du.x), fabsf(dv.x));
            const float tt1 = fmaxf(fabsf(du.y), fabsf(dv.y));
            const v2f tt = (v2f){tt0, tt1};
            const v2f d1 = tt + one2;
            const float rn0 = r - tt0;
            const float rn1 = r - tt1;
            const v2f d2 = (v2f){1.f + fabsf(rn0), 1.f + fabsf(rn1)};
            const v2f dd  = d1 * d2;
            const v2f num = d2 - d1;
            const v2f rc  = (v2f){__builtin_amdgcn_rcpf(dd.x),
                                  __builtin_amdgcn_rcpf(dd.y)};
            acc[k] = __builtin_elementwise_fma(num, rc, acc[k]);
        }
    }

    float a1[KC_A];
    #pragma unroll
    for (int k = 0; k < KC_A; ++k) a1[k] = acc[k].x + acc[k].y;

    // KC=8 butterfly (validated): value (lane>>3)&7 in a1[0] at (lane&7)==0
    {
        #pragma unroll
        for (int k = 0; k < 4; ++k) {
            const bool hi = lane & 32;
            const float send = hi ? a1[k]   : a1[k+4];
            const float keep = hi ? a1[k+4] : a1[k];
            a1[k] = keep + __shfl_xor(send, 32, 64);
        }
        #pragma unroll
        for (int k = 0; k < 2; ++k) {
            const bool hi = lane & 16;
            const float send = hi ? a1[k]   : a1[k+2];
            const float keep = hi ? a1[k+2] : a1[k];
            a1[k] = keep + __shfl_xor(send, 16, 64);
        }
        {
            const bool hi = lane & 8;
            const float send = hi ? a1[0] : a1[1];
            const float keep = hi ? a1[1] : a1[0];
            a1[0] = keep + __shfl_xor(send, 8, 64);
        }
        a1[0] += __shfl_xor(a1[0], 4, 64);
        a1[0] += __shfl_xor(a1[0], 2, 64);
        a1[0] += __shfl_xor(a1[0], 1, 64);
    }
    // Each A wave owns its own 8 centers: no LDS, no __syncthreads needed.
    if ((lane & 7) == 0) {
        atomicAdd(&out[outBase + (lane >> 3)], a1[0]);
    }
}

__global__ __launch_bounds__(256) void tpl_kernel(float* __restrict__ out)
{
    __shared__ float red[256];
    float s = 0.f;
    for (int i = threadIdx.x; i < NB*64; i += 256) {
        const int b = i >> 6, k = i & 63;
        const float d = out[b*128 + k] - out[b*128 + 64 + k];
        s = fmaf(d, d, s);
    }
    red[threadIdx.x] = s;
    __syncthreads();
    for (int w = 128; w > 0; w >>= 1) {
        if (threadIdx.x < w) red[threadIdx.x] += red[threadIdx.x + w];
        __syncthreads();
    }
    if (threadIdx.x == 0) out[NB*128] = -red[0];
}

extern "C" void kernel_launch(void* const* d_in, const int* in_sizes, int n_in,
                              void* d_out, int out_size, void* d_ws, size_t ws_size,
                              hipStream_t stream) {
    const float* up0     = (const float*)d_in[0];
    const float* down0   = (const float*)d_in[1];
    const float* ext0    = (const float*)d_in[2];
    const float* ext1    = (const float*)d_in[3];
    const float* centers = (const float*)d_in[4];
    const float* radius  = (const float*)d_in[5];
    float* out = (float*)d_out;

    // accumulator region must start at zero (harness poisons d_out with 0xAA)
    hipMemsetAsync(out, 0, NB * 128 * sizeof(float), stream);

    hat_kernel<<<dim3(256 + 1024), dim3(256), 0, stream>>>(
        up0, down0, ext0, ext1, centers, radius, out);
    tpl_kernel<<<1, 256, 0, stream>>>(out);
}

// Round 8
// 109.550 us; speedup vs baseline: 1.1170x; 1.0016x over previous
//
#include <hip/hip_runtime.h>

typedef float v2f __attribute__((ext_vector_type(2)));

#define NB 32
#define N0 20000
#define N1 10000
#define N2 10000
#define NF4_A 10000        // float4s per (b, side) beta_0 stream
#define NF4_E0 5000        // float4s of ext0 per b
#define NF4_E 10000        // float4s of ext0+ext1 per b
#define NCH 157            // ceil(10000/64): 64-float4 chunks per A stream
#define T_A 14             // A-role chunk stride (1792 A-blocks)
#define KC_A 8             // centers per A wave
#define KC_B 16            // centers per E block
#define NBINS 4096
#define SENT 3.0e4f        // sentinel: per-term contribution ~ -1e-10

// R8 = R7 + two fixes from the R7 post-mortem (idle 17us, occupancy 31%):
//  (1) grid 1280 -> 2048 (256 E + 1792 A, T_A=14): 8 blocks/CU = 32
//      waves/CU removes the 62.5% occupancy cap; 7 A-waves/SIMD cover the
//      E-wave's stalls. LDS 8x16.9KB = 135KB <= 160KB, VGPR 32 <= 64.
//  (2) E-build loads: unconditional clamped pointer-select + prefetch one
//      iteration ahead (independent of the LDS atomics -> issues under
//      them), removing the per-iteration latency exposure.
// E eval/butterfly/reduce = R7/R2-validated verbatim; A path = R6-validated
// with T_A=14. Roles XCD-even (blockIdx%8 = XCD; R1 lesson).
__global__ __launch_bounds__(256, 8) void hat_kernel(
    const float* __restrict__ up0, const float* __restrict__ down0,
    const float* __restrict__ ext0, const float* __restrict__ ext1,
    const float* __restrict__ centers, const float* __restrict__ radius,
    float* __restrict__ out)
{
    const int tid  = threadIdx.x;
    const int lane = tid & 63;
    const int wave = tid >> 6;
    const float r  = fabsf(radius[0]);
    const int slot = blockIdx.x;

    __shared__ unsigned hist[NBINS];     // 16 KB (E-role)
    __shared__ float    red[4 * KC_B];   // E-role cross-wave reduction

    if (slot < 256) {
        // ============ E-role: ext points, 1-D binned (R7-validated) ========
        const int id   = slot;
        const int cc   = id & 3;         // 4 chunks of 16 centers
        const int side = (id >> 2) & 1;  // 0 = up (use y), 1 = down (use x)
        const int b    = id >> 3;
        const int cbase = cc * KC_B;

        for (int j = tid; j < NBINS; j += 256) hist[j] = 0;
        __syncthreads();

        // Build: one pass over ext0|ext1 as float4 (2 points each).
        // Unconditional clamped pointer-select load, prefetched 1 iter ahead.
        const float4* e0 = (const float4*)(ext0 + (size_t)b * (N1*2));
        const float4* e1 = (const float4*)(ext1 + (size_t)b * (N2*2));
        #define EPTR(I) ((I) < NF4_E0 ? (e0 + (I)) : (e1 + ((I) - NF4_E0)))
        float4 q = *EPTR(tid);
        for (int i = tid; i < NF4_E; i += 256) {
            const float4 qc = q;
            q = *EPTR(min(i + 256, NF4_E - 1));
            const float vv0 = (side == 0) ? qc.y : qc.x;
            const float vv1 = (side == 0) ? qc.w : qc.z;
            int b0 = (int)(vv0 * (float)NBINS);
            int b1 = (int)(vv1 * (float)NBINS);
            b0 = min(max(b0, 0), NBINS - 1);
            b1 = min(max(b1, 0), NBINS - 1);
            atomicAdd(&hist[b0], 1u);
            atomicAdd(&hist[b1], 1u);
        }
        #undef EPTR
        __syncthreads();

        // centers: n_k(vv) = max(|1-(cx+cy)|, 2|vv - (1+cx-cy)/2|)
        float Ak[KC_B], mk[KC_B];
        #pragma unroll
        for (int k = 0; k < KC_B; ++k) {
            const float cx = centers[2*(cbase+k)];
            const float cy = centers[2*(cbase+k)+1];
            Ak[k] = fabsf(1.0f - (cx + cy));
            mk[k] = 0.5f * (1.0f + (cx - cy));
        }

        float part[KC_B];
        #pragma unroll
        for (int k = 0; k < KC_B; ++k) part[k] = 0.f;

        #pragma unroll
        for (int jj = 0; jj < NBINS/256; ++jj) {
            const int j = jj*256 + tid;
            const float cntf = (float)hist[j];
            const float vvj  = ((float)j + 0.5f) * (1.0f/(float)NBINS);
            #pragma unroll
            for (int k = 0; k < KC_B; ++k) {
                const float s  = vvj - mk[k];
                const float tt = fmaxf(Ak[k], 2.0f*fabsf(s));
                const float d1 = 1.0f + tt;
                const float rn = r - tt;
                const float d2 = 1.0f + fabsf(rn);
                const float rc = __builtin_amdgcn_rcpf(d1 * d2);
                part[k] = fmaf(cntf * (d2 - d1), rc, part[k]);
            }
        }

        // KC=16 butterfly (R2-validated): center (lane>>2)&15 in part[0]
        {
            #pragma unroll
            for (int k = 0; k < 8; ++k) {
                const bool hi = lane & 32;
                const float send = hi ? part[k]   : part[k+8];
                const float keep = hi ? part[k+8] : part[k];
                part[k] = keep + __shfl_xor(send, 32, 64);
            }
            #pragma unroll
            for (int k = 0; k < 4; ++k) {
                const bool hi = lane & 16;
                const float send = hi ? part[k]   : part[k+4];
                const float keep = hi ? part[k+4] : part[k];
                part[k] = keep + __shfl_xor(send, 16, 64);
            }
            #pragma unroll
            for (int k = 0; k < 2; ++k) {
                const bool hi = lane & 8;
                const float send = hi ? part[k]   : part[k+2];
                const float keep = hi ? part[k+2] : part[k];
                part[k] = keep + __shfl_xor(send, 8, 64);
            }
            {
                const bool hi = lane & 4;
                const float send = hi ? part[0] : part[1];
                const float keep = hi ? part[1] : part[0];
                part[0] = keep + __shfl_xor(send, 4, 64);
            }
            part[0] += __shfl_xor(part[0], 2, 64);
            part[0] += __shfl_xor(part[0], 1, 64);
        }
        if ((lane & 3) == 0) red[wave * KC_B + (lane >> 2)] = part[0];
        __syncthreads();
        if (tid < KC_B) {
            const float s = red[tid] + red[KC_B + tid] + red[2*KC_B + tid] + red[3*KC_B + tid];
            atomicAdd(&out[b*128 + side*64 + cbase + tid], s);
        }
        return;
    }

    // ============ A-role: beta_0 points, exact 2-D (R6-validated) ============
    // aid = ((b*2 + side)*2 + half)*14 + tchunk   (1792 total)
    const int aid    = slot - 256;
    const int tchunk = aid % T_A;
    const int rest   = aid / T_A;
    const int half   = rest & 1;
    const int side   = (rest >> 1) & 1;
    const int b      = rest >> 2;
    const int cbase  = (half * 4 + wave) * KC_A;   // per-wave center group
    const int outBase = b*128 + side*64 + cbase;

    v2f nuc[KC_A], nvc[KC_A];
    #pragma unroll
    for (int k = 0; k < KC_A; ++k) {
        const float cx = centers[2*(cbase+k)];
        const float cy = centers[2*(cbase+k)+1];
        nuc[k] = (v2f){-(cx + cy), -(cx + cy)};
        nvc[k] = (v2f){-(cx - cy), -(cx - cy)};
    }

    const float4* base0 = (const float4*)((side == 0 ? up0 : down0) + (size_t)b * (N0*2));

    v2f acc[KC_A];
    #pragma unroll
    for (int k = 0; k < KC_A; ++k) acc[k] = (v2f){0.f, 0.f};
    const v2f one2 = (v2f){1.f, 1.f};

    // Unconditional clamped load, prefetched one iteration ahead.
    float4 q = base0[min(tchunk*64 + lane, NF4_A - 1)];
    for (int t = tchunk; t < NCH; t += T_A) {
        const float4 qc = q;
        const int tn = t + T_A;
        if (tn < NCH) {                       // wave-uniform
            q = base0[min(tn*64 + lane, NF4_A - 1)];
        }

        v2f u_ = (v2f){qc.x + qc.y, qc.z + qc.w};
        v2f v_ = (v2f){qc.x - qc.y, qc.z - qc.w};
        if (t*64 + 63 >= NF4_A) {             // wave-uniform: only t==156
            const bool bad = (t*64 + lane) >= NF4_A;
            u_.x = bad ? SENT : u_.x;  u_.y = bad ? SENT : u_.y;
            v_.x = bad ? 0.f  : v_.x;  v_.y = bad ? 0.f  : v_.y;
        }

        #pragma unroll
        for (int k = 0; k < KC_A; ++k) {
            const v2f du = u_ + nuc[k];
            const v2f dv = v_ + nvc[k];
            const float tt0 = fmaxf(fabsf(du.x), fabsf(dv.x));
            const float tt1 = fmaxf(fabsf(du.y), fabsf(dv.y));
            const v2f tt = (v2f){tt0, tt1};
            const v2f d1 = tt + one2;
            const float rn0 = r - tt0;
            const float rn1 = r - tt1;
            const v2f d2 = (v2f){1.f + fabsf(rn0), 1.f + fabsf(rn1)};
            const v2f dd  = d1 * d2;
            const v2f num = d2 - d1;
            const v2f rc  = (v2f){__builtin_amdgcn_rcpf(dd.x),
                                  __builtin_amdgcn_rcpf(dd.y)};
            acc[k] = __builtin_elementwise_fma(num, rc, acc[k]);
        }
    }

    float a1[KC_A];
    #pragma unroll
    for (int k = 0; k < KC_A; ++k) a1[k] = acc[k].x + acc[k].y;

    // KC=8 butterfly (validated): value (lane>>3)&7 in a1[0] at (lane&7)==0
    {
        #pragma unroll
        for (int k = 0; k < 4; ++k) {
            const bool hi = lane & 32;
            const float send = hi ? a1[k]   : a1[k+4];
            const float keep = hi ? a1[k+4] : a1[k];
            a1[k] = keep + __shfl_xor(send, 32, 64);
        }
        #pragma unroll
        for (int k = 0; k < 2; ++k) {
            const bool hi = lane & 16;
            const float send = hi ? a1[k]   : a1[k+2];
            const float keep = hi ? a1[k+2] : a1[k];
            a1[k] = keep + __shfl_xor(send, 16, 64);
        }
        {
            const bool hi = lane & 8;
            const float send = hi ? a1[0] : a1[1];
            const float keep = hi ? a1[1] : a1[0];
            a1[0] = keep + __shfl_xor(send, 8, 64);
        }
        a1[0] += __shfl_xor(a1[0], 4, 64);
        a1[0] += __shfl_xor(a1[0], 2, 64);
        a1[0] += __shfl_xor(a1[0], 1, 64);
    }
    // Each A wave owns its own 8 centers: no LDS, no __syncthreads needed.
    if ((lane & 7) == 0) {
        atomicAdd(&out[outBase + (lane >> 3)], a1[0]);
    }
}

__global__ __launch_bounds__(256) void tpl_kernel(float* __restrict__ out)
{
    __shared__ float red[256];
    float s = 0.f;
    for (int i = threadIdx.x; i < NB*64; i += 256) {
        const int b = i >> 6, k = i & 63;
        const float d = out[b*128 + k] - out[b*128 + 64 + k];
        s = fmaf(d, d, s);
    }
    red[threadIdx.x] = s;
    __syncthreads();
    for (int w = 128; w > 0; w >>= 1) {
        if (threadIdx.x < w) red[threadIdx.x] += red[threadIdx.x + w];
        __syncthreads();
    }
    if (threadIdx.x == 0) out[NB*128] = -red[0];
}

extern "C" void kernel_launch(void* const* d_in, const int* in_sizes, int n_in,
                              void* d_out, int out_size, void* d_ws, size_t ws_size,
                              hipStream_t stream) {
    const float* up0     = (const float*)d_in[0];
    const float* down0   = (const float*)d_in[1];
    const float* ext0    = (const float*)d_in[2];
    const float* ext1    = (const float*)d_in[3];
    const float* centers = (const float*)d_in[4];
    const float* radius  = (const float*)d_in[5];
    float* out = (float*)d_out;

    // accumulator region must start at zero (harness poisons d_out with 0xAA)
    hipMemsetAsync(out, 0, NB * 128 * sizeof(float), stream);

    hat_kernel<<<dim3(256 + 1792), dim3(256), 0, stream>>>(
        up0, down0, ext0, ext1, centers, radius, out);
    tpl_kernel<<<1, 256, 0, stream>>>(out);
}